// Round 3
// 322.292 us; speedup vs baseline: 1.1052x; 1.1052x over previous
//
#include <hip/hip_runtime.h>
#include <math.h>

#define Hd 768
#define Bb 8
#define Ll 256
#define Kk 32
#define LG 128

using half4 = __attribute__((ext_vector_type(4))) _Float16;
using half8 = __attribute__((ext_vector_type(8))) _Float16;
using f32x4 = __attribute__((ext_vector_type(4))) float;

__device__ __forceinline__ float sigm(float z) { return 1.f / (1.f + __expf(-z)); }

// ---------------- multi-segment f32 -> f16 conversion (one dispatch) -----------
struct ConvArgs {
    const float* src[8];
    _Float16*    dst[8];
    int cum[9];     // cumulative chunk counts (chunks of 8 elements)
    int sstr[8];    // src row stride (elements)
    int dstr[8];    // dst row stride (elements)
    int rl[8];      // row length (elements, %8==0)
};

__global__ __launch_bounds__(256) void conv_multi(ConvArgs a) {
    int c = blockIdx.x * 256 + threadIdx.x;
    if (c >= a.cum[8]) return;
    int s = 0;
    while (c >= a.cum[s + 1]) ++s;
    const int lc  = c - a.cum[s];
    const unsigned cpr = (unsigned)(a.rl[s] >> 3);
    const unsigned row = (unsigned)lc / cpr;
    const int col = (lc - (int)(row * cpr)) * 8;
    const float* sp = a.src[s] + (size_t)row * a.sstr[s] + col;
    float4 v0 = *(const float4*)sp;
    float4 v1 = *(const float4*)(sp + 4);
    half8 h;
    h[0] = (_Float16)v0.x; h[1] = (_Float16)v0.y; h[2] = (_Float16)v0.z; h[3] = (_Float16)v0.w;
    h[4] = (_Float16)v1.x; h[5] = (_Float16)v1.y; h[6] = (_Float16)v1.z; h[7] = (_Float16)v1.w;
    *(half8*)(a.dst[s] + (size_t)row * a.dstr[s] + col) = h;
}

// ---------------- generic f16 MFMA GEMM (used for gctx) ------------------------
__global__ __launch_bounds__(256) void gemm_f16(
    const _Float16* __restrict__ A, int lda, long sA,
    const _Float16* __restrict__ W, int ldw, long sW,
    const float* __restrict__ bias,
    float* __restrict__ C, int ldc, long sC,
    _Float16* __restrict__ C2, int ldc2, long sC2,
    int Kd, int kvsplit,
    _Float16* __restrict__ K16, _Float16* __restrict__ VT16)
{
    __shared__ _Float16 As[128][72];
    __shared__ _Float16 Ws[64][72];

    const int t    = threadIdx.x;
    const int w    = t >> 6;
    const int lane = t & 63;
    const int quad = lane >> 4;
    const int l16  = lane & 15;
    const int bm   = blockIdx.y * 128;
    const int bn   = blockIdx.x * 64;
    const int z    = blockIdx.z;
    A += (size_t)z * sA;
    W += (size_t)z * sW;

    const int sr = t >> 3;
    const int sk = (t & 7) * 8;

    f32x4 acc[2][4] = {};

    for (int k0 = 0; k0 < Kd; k0 += 64) {
        half8 av[4], wv[2];
        #pragma unroll
        for (int i = 0; i < 4; ++i)
            av[i] = *(const half8*)(A + (size_t)(bm + i * 32 + sr) * lda + k0 + sk);
        #pragma unroll
        for (int i = 0; i < 2; ++i)
            wv[i] = *(const half8*)(W + (size_t)(bn + i * 32 + sr) * ldw + k0 + sk);
        __syncthreads();
        #pragma unroll
        for (int i = 0; i < 4; ++i) *(half8*)&As[i * 32 + sr][sk] = av[i];
        #pragma unroll
        for (int i = 0; i < 2; ++i) *(half8*)&Ws[i * 32 + sr][sk] = wv[i];
        __syncthreads();
        #pragma unroll
        for (int kk = 0; kk < 2; ++kk) {
            half8 af[2], bf[4];
            af[0] = *(const half8*)&As[w * 32 + l16][kk * 32 + quad * 8];
            af[1] = *(const half8*)&As[w * 32 + 16 + l16][kk * 32 + quad * 8];
            #pragma unroll
            for (int j = 0; j < 4; ++j)
                bf[j] = *(const half8*)&Ws[j * 16 + l16][kk * 32 + quad * 8];
            #pragma unroll
            for (int rt = 0; rt < 2; ++rt)
                #pragma unroll
                for (int j = 0; j < 4; ++j)
                    acc[rt][j] = __builtin_amdgcn_mfma_f32_16x16x32_f16(
                        af[rt], bf[j], acc[rt][j], 0, 0, 0);
        }
    }

    #pragma unroll
    for (int rt = 0; rt < 2; ++rt) {
        #pragma unroll
        for (int j = 0; j < 4; ++j) {
            const int col  = bn + j * 16 + l16;
            const int row0 = bm + w * 32 + rt * 16 + quad * 4;
            const float bv = bias ? bias[col] : 0.f;
            if (kvsplit) {
                if (col < 768) {
                    #pragma unroll
                    for (int r = 0; r < 4; ++r)
                        K16[(size_t)(row0 + r) * 768 + col] = (_Float16)(acc[rt][j][r] + bv);
                } else {
                    const int b = row0 >> 7, h = col - 768, m0 = row0 & 127;
                    half4 hv;
                    #pragma unroll
                    for (int r = 0; r < 4; ++r) hv[r] = (_Float16)(acc[rt][j][r] + bv);
                    *(half4*)(VT16 + ((size_t)(b * 768 + h)) * 128 + m0) = hv;
                }
            } else {
                #pragma unroll
                for (int r = 0; r < 4; ++r) {
                    const float v = acc[rt][j][r] + bv;
                    const size_t rr = (size_t)(row0 + r);
                    if (C)  C[(size_t)z * sC + rr * ldc + col] = v;
                    if (C2) C2[(size_t)z * sC2 + rr * ldc2 + col] = (_Float16)v;
                }
            }
        }
    }
}

// ---------------- merged 3-way GEMM: q, kv, E in one dispatch ------------------
struct G3Desc {
    const _Float16* A;
    const _Float16* W;
    const float* bias;
    void* o0;
    void* o1;
    int lda, ldw, mode, nbx;   // mode 0: f16 out (ld 768); 1: kvsplit; 2: f32 out (ld 768)
};
struct G3Args { G3Desc d[3]; int cum[4]; };

__global__ __launch_bounds__(256) void gemm3(G3Args ga) {
    __shared__ _Float16 As[128][72];
    __shared__ _Float16 Ws[64][72];

    const int t    = threadIdx.x;
    const int w    = t >> 6;
    const int lane = t & 63;
    const int quad = lane >> 4;
    const int l16  = lane & 15;

    int s = 0;
    const int bid = blockIdx.x;
    while (bid >= ga.cum[s + 1]) ++s;
    const int local = bid - ga.cum[s];
    const int nbx   = ga.d[s].nbx;
    const int by    = local / nbx;
    const int bx    = local - by * nbx;
    const int bm    = by * 128;
    const int bn    = bx * 64;
    const _Float16* A = ga.d[s].A;
    const _Float16* W = ga.d[s].W;
    const int lda = ga.d[s].lda;
    const int ldw = ga.d[s].ldw;

    const int sr = t >> 3;
    const int sk = (t & 7) * 8;

    f32x4 acc[2][4] = {};

    for (int k0 = 0; k0 < 768; k0 += 64) {
        half8 av[4], wv[2];
        #pragma unroll
        for (int i = 0; i < 4; ++i)
            av[i] = *(const half8*)(A + (size_t)(bm + i * 32 + sr) * lda + k0 + sk);
        #pragma unroll
        for (int i = 0; i < 2; ++i)
            wv[i] = *(const half8*)(W + (size_t)(bn + i * 32 + sr) * ldw + k0 + sk);
        __syncthreads();
        #pragma unroll
        for (int i = 0; i < 4; ++i) *(half8*)&As[i * 32 + sr][sk] = av[i];
        #pragma unroll
        for (int i = 0; i < 2; ++i) *(half8*)&Ws[i * 32 + sr][sk] = wv[i];
        __syncthreads();
        #pragma unroll
        for (int kk = 0; kk < 2; ++kk) {
            half8 af[2], bf[4];
            af[0] = *(const half8*)&As[w * 32 + l16][kk * 32 + quad * 8];
            af[1] = *(const half8*)&As[w * 32 + 16 + l16][kk * 32 + quad * 8];
            #pragma unroll
            for (int j = 0; j < 4; ++j)
                bf[j] = *(const half8*)&Ws[j * 16 + l16][kk * 32 + quad * 8];
            #pragma unroll
            for (int rt = 0; rt < 2; ++rt)
                #pragma unroll
                for (int j = 0; j < 4; ++j)
                    acc[rt][j] = __builtin_amdgcn_mfma_f32_16x16x32_f16(
                        af[rt], bf[j], acc[rt][j], 0, 0, 0);
        }
    }

    const int mode = ga.d[s].mode;
    const float* bias = ga.d[s].bias;
    #pragma unroll
    for (int rt = 0; rt < 2; ++rt) {
        #pragma unroll
        for (int j = 0; j < 4; ++j) {
            const int col  = bn + j * 16 + l16;
            const int row0 = bm + w * 32 + rt * 16 + quad * 4;
            const float bv = bias ? bias[col] : 0.f;
            if (mode == 0) {
                _Float16* C2 = (_Float16*)ga.d[s].o0;
                #pragma unroll
                for (int r = 0; r < 4; ++r)
                    C2[(size_t)(row0 + r) * 768 + col] = (_Float16)(acc[rt][j][r] + bv);
            } else if (mode == 1) {
                _Float16* K16  = (_Float16*)ga.d[s].o0;
                _Float16* VT16 = (_Float16*)ga.d[s].o1;
                if (col < 768) {
                    #pragma unroll
                    for (int r = 0; r < 4; ++r)
                        K16[(size_t)(row0 + r) * 768 + col] = (_Float16)(acc[rt][j][r] + bv);
                } else {
                    const int b = row0 >> 7, h = col - 768, m0 = row0 & 127;
                    half4 hv;
                    #pragma unroll
                    for (int r = 0; r < 4; ++r) hv[r] = (_Float16)(acc[rt][j][r] + bv);
                    *(half4*)(VT16 + ((size_t)(b * 768 + h)) * 128 + m0) = hv;
                }
            } else {
                float* C = (float*)ga.d[s].o0;
                #pragma unroll
                for (int r = 0; r < 4; ++r)
                    C[(size_t)(row0 + r) * 768 + col] = acc[rt][j][r] + bv;
            }
        }
    }
}

// ---------------- fused scores + softmax ---------------------------------------
// block: 64 q-rows x all 128 keys of one batch. grid (4, 8).
__global__ __launch_bounds__(256) void attn_scores_sm(
    const _Float16* __restrict__ Q, const _Float16* __restrict__ Kt,
    _Float16* __restrict__ P)
{
    __shared__ _Float16 As[64][72];
    __shared__ _Float16 Ws[128][72];

    const int t    = threadIdx.x;
    const int w    = t >> 6;
    const int lane = t & 63;
    const int quad = lane >> 4;
    const int l16  = lane & 15;
    const int z    = blockIdx.y;
    const int bm   = blockIdx.x * 64;
    const _Float16* A = Q  + (size_t)z * 256 * 768 + (size_t)bm * 768;
    const _Float16* W = Kt + (size_t)z * 128 * 768;

    const int sr = t >> 3;
    const int sk = (t & 7) * 8;

    f32x4 acc[8] = {};

    for (int k0 = 0; k0 < 768; k0 += 64) {
        half8 av[2], wv[4];
        #pragma unroll
        for (int i = 0; i < 2; ++i)
            av[i] = *(const half8*)(A + (size_t)(i * 32 + sr) * 768 + k0 + sk);
        #pragma unroll
        for (int i = 0; i < 4; ++i)
            wv[i] = *(const half8*)(W + (size_t)(i * 32 + sr) * 768 + k0 + sk);
        __syncthreads();
        #pragma unroll
        for (int i = 0; i < 2; ++i) *(half8*)&As[i * 32 + sr][sk] = av[i];
        #pragma unroll
        for (int i = 0; i < 4; ++i) *(half8*)&Ws[i * 32 + sr][sk] = wv[i];
        __syncthreads();
        #pragma unroll
        for (int kk = 0; kk < 2; ++kk) {
            half8 af = *(const half8*)&As[w * 16 + l16][kk * 32 + quad * 8];
            #pragma unroll
            for (int j = 0; j < 8; ++j) {
                half8 bf = *(const half8*)&Ws[j * 16 + l16][kk * 32 + quad * 8];
                acc[j] = __builtin_amdgcn_mfma_f32_16x16x32_f16(af, bf, acc[j], 0, 0, 0);
            }
        }
    }

    const float scale = 0.03608439182435161f;   // 1/sqrt(768)
    #pragma unroll
    for (int r = 0; r < 4; ++r) {
        float v[8];
        float mx = -1e30f;
        #pragma unroll
        for (int j = 0; j < 8; ++j) { v[j] = acc[j][r] * scale; mx = fmaxf(mx, v[j]); }
        #pragma unroll
        for (int off = 8; off; off >>= 1) mx = fmaxf(mx, __shfl_xor(mx, off, 16));
        float sum = 0.f;
        #pragma unroll
        for (int j = 0; j < 8; ++j) { v[j] = __expf(v[j] - mx); sum += v[j]; }
        #pragma unroll
        for (int off = 8; off; off >>= 1) sum += __shfl_xor(sum, off, 16);
        const float inv = 1.f / sum;
        const int row = bm + w * 16 + quad * 4 + r;
        _Float16* Pr = P + (size_t)z * 256 * 128 + (size_t)row * 128;
        #pragma unroll
        for (int j = 0; j < 8; ++j) Pr[j * 16 + l16] = (_Float16)(v[j] * inv);
    }
}

// ---------------- t1 GEMM with fused gate1 epilogue ----------------------------
__global__ __launch_bounds__(256) void gemm_gate1(
    const _Float16* __restrict__ A,   // xg16 [2048][1536]
    const _Float16* __restrict__ W,   // Wg116 [768][1536]
    const float* __restrict__ bias,   // bg1
    const float* __restrict__ X,      // x fp32
    const float* __restrict__ GC,     // gctx fp32
    float* __restrict__ H1,
    _Float16* __restrict__ H16)
{
    __shared__ _Float16 As[128][72];
    __shared__ _Float16 Ws[64][72];

    const int t    = threadIdx.x;
    const int w    = t >> 6;
    const int lane = t & 63;
    const int quad = lane >> 4;
    const int l16  = lane & 15;
    const int bm   = blockIdx.y * 128;
    const int bn   = blockIdx.x * 64;

    const int sr = t >> 3;
    const int sk = (t & 7) * 8;

    f32x4 acc[2][4] = {};

    for (int k0 = 0; k0 < 1536; k0 += 64) {
        half8 av[4], wv[2];
        #pragma unroll
        for (int i = 0; i < 4; ++i)
            av[i] = *(const half8*)(A + (size_t)(bm + i * 32 + sr) * 1536 + k0 + sk);
        #pragma unroll
        for (int i = 0; i < 2; ++i)
            wv[i] = *(const half8*)(W + (size_t)(bn + i * 32 + sr) * 1536 + k0 + sk);
        __syncthreads();
        #pragma unroll
        for (int i = 0; i < 4; ++i) *(half8*)&As[i * 32 + sr][sk] = av[i];
        #pragma unroll
        for (int i = 0; i < 2; ++i) *(half8*)&Ws[i * 32 + sr][sk] = wv[i];
        __syncthreads();
        #pragma unroll
        for (int kk = 0; kk < 2; ++kk) {
            half8 af[2], bf[4];
            af[0] = *(const half8*)&As[w * 32 + l16][kk * 32 + quad * 8];
            af[1] = *(const half8*)&As[w * 32 + 16 + l16][kk * 32 + quad * 8];
            #pragma unroll
            for (int j = 0; j < 4; ++j)
                bf[j] = *(const half8*)&Ws[j * 16 + l16][kk * 32 + quad * 8];
            #pragma unroll
            for (int rt = 0; rt < 2; ++rt)
                #pragma unroll
                for (int j = 0; j < 4; ++j)
                    acc[rt][j] = __builtin_amdgcn_mfma_f32_16x16x32_f16(
                        af[rt], bf[j], acc[rt][j], 0, 0, 0);
        }
    }

    #pragma unroll
    for (int rt = 0; rt < 2; ++rt) {
        #pragma unroll
        for (int j = 0; j < 4; ++j) {
            const int col  = bn + j * 16 + l16;
            const int row0 = bm + w * 32 + rt * 16 + quad * 4;
            const float bv = bias[col];
            #pragma unroll
            for (int r = 0; r < 4; ++r) {
                const size_t off = (size_t)(row0 + r) * 768 + col;
                const float g = sigm(acc[rt][j][r] + bv);
                const float o = g * X[off] + (1.f - g) * GC[off];
                H1[off]  = o;
                H16[off] = (_Float16)o;
            }
        }
    }
}

// ---------------- D GEMM with fused final_combine epilogue ---------------------
// out[b,l,k,h] = sig(D[b,l,h] + E[b,k,h]) * h1[b,l,h] + (1-sig) * s[b,k,h]
__global__ __launch_bounds__(256) void gemm_final(
    const _Float16* __restrict__ A,   // h116 [2048][768]
    const _Float16* __restrict__ W,   // Wg2a16 [768][768]
    const float* __restrict__ bias,   // bg2
    const float* __restrict__ Ebuf,   // [256][768] fp32
    const float* __restrict__ Sbuf,   // s fp32 [256][768]
    const float* __restrict__ H1,     // h1 fp32 [2048][768]
    float* __restrict__ out)
{
    __shared__ union {
        struct { _Float16 As[128][72]; _Float16 Ws[64][72]; } a;
        float Ds[128][76];            // 76: float4-aligned, 2-way-max bank pattern
    } u;
    __shared__ float Es[32][64];
    __shared__ float Ss[32][64];

    const int t    = threadIdx.x;
    const int w    = t >> 6;
    const int lane = t & 63;
    const int quad = lane >> 4;
    const int l16  = lane & 15;
    const int bm   = blockIdx.y * 128;
    const int bn   = blockIdx.x * 64;
    const int bK   = (bm >> 8) * 32;  // batch * 32 row base into E/s

    const int sr = t >> 3;
    const int sk = (t & 7) * 8;

    // stage E and s slices (ready since gemm3 / input)
    #pragma unroll
    for (int i = 0; i < 2; ++i) {
        const int idx = t + i * 256;
        const int k = idx >> 4, c = (idx & 15) * 4;
        *(float4*)&Es[k][c] = *(const float4*)(Ebuf + (size_t)(bK + k) * 768 + bn + c);
        *(float4*)&Ss[k][c] = *(const float4*)(Sbuf + (size_t)(bK + k) * 768 + bn + c);
    }

    f32x4 acc[2][4] = {};

    for (int k0 = 0; k0 < 768; k0 += 64) {
        half8 av[4], wv[2];
        #pragma unroll
        for (int i = 0; i < 4; ++i)
            av[i] = *(const half8*)(A + (size_t)(bm + i * 32 + sr) * 768 + k0 + sk);
        #pragma unroll
        for (int i = 0; i < 2; ++i)
            wv[i] = *(const half8*)(W + (size_t)(bn + i * 32 + sr) * 768 + k0 + sk);
        __syncthreads();
        #pragma unroll
        for (int i = 0; i < 4; ++i) *(half8*)&u.a.As[i * 32 + sr][sk] = av[i];
        #pragma unroll
        for (int i = 0; i < 2; ++i) *(half8*)&u.a.Ws[i * 32 + sr][sk] = wv[i];
        __syncthreads();
        #pragma unroll
        for (int kk = 0; kk < 2; ++kk) {
            half8 af[2], bf[4];
            af[0] = *(const half8*)&u.a.As[w * 32 + l16][kk * 32 + quad * 8];
            af[1] = *(const half8*)&u.a.As[w * 32 + 16 + l16][kk * 32 + quad * 8];
            #pragma unroll
            for (int j = 0; j < 4; ++j)
                bf[j] = *(const half8*)&u.a.Ws[j * 16 + l16][kk * 32 + quad * 8];
            #pragma unroll
            for (int rt = 0; rt < 2; ++rt)
                #pragma unroll
                for (int j = 0; j < 4; ++j)
                    acc[rt][j] = __builtin_amdgcn_mfma_f32_16x16x32_f16(
                        af[rt], bf[j], acc[rt][j], 0, 0, 0);
        }
    }

    __syncthreads();   // done reading As/Ws — union memory becomes Ds
    #pragma unroll
    for (int rt = 0; rt < 2; ++rt) {
        #pragma unroll
        for (int j = 0; j < 4; ++j) {
            const int col = j * 16 + l16;
            const float bv = bias[bn + col];
            #pragma unroll
            for (int r = 0; r < 4; ++r)
                u.Ds[w * 32 + rt * 16 + quad * 4 + r][col] = acc[rt][j][r] + bv;
        }
    }
    __syncthreads();

    // re-layout: thread owns 8 consecutive rows x one float4 column group
    const int c  = (t & 15) * 4;
    const int r0 = (t >> 4) * 8;
    float4 d[8], h[8];
    #pragma unroll
    for (int rr = 0; rr < 8; ++rr) {
        d[rr] = *(const float4*)&u.Ds[r0 + rr][c];
        h[rr] = *(const float4*)(H1 + (size_t)(bm + r0 + rr) * 768 + bn + c);
    }
    float* ob = out + (size_t)(bm + r0) * 32 * 768 + bn + c;
    for (int k = 0; k < 32; ++k) {
        const float4 e  = *(const float4*)&Es[k][c];
        const float4 sv = *(const float4*)&Ss[k][c];
        #pragma unroll
        for (int rr = 0; rr < 8; ++rr) {
            float4 o; float g;
            g = sigm(d[rr].x + e.x); o.x = g * h[rr].x + (1.f - g) * sv.x;
            g = sigm(d[rr].y + e.y); o.y = g * h[rr].y + (1.f - g) * sv.y;
            g = sigm(d[rr].z + e.z); o.z = g * h[rr].z + (1.f - g) * sv.z;
            g = sigm(d[rr].w + e.w); o.w = g * h[rr].w + (1.f - g) * sv.w;
            *(float4*)(ob + (size_t)(rr * 32 + k) * 768) = o;
        }
    }
}

extern "C" void kernel_launch(void* const* d_in, const int* in_sizes, int n_in,
                              void* d_out, int out_size, void* d_ws, size_t ws_size,
                              hipStream_t stream) {
    const float* x   = (const float*)d_in[0];
    const float* s   = (const float*)d_in[1];
    const float* g   = (const float*)d_in[2];
    const float* Wq  = (const float*)d_in[3];
    const float* bq  = (const float*)d_in[4];
    const float* Wkv = (const float*)d_in[5];
    const float* bkv = (const float*)d_in[6];
    const float* Wg1 = (const float*)d_in[7];
    const float* bg1 = (const float*)d_in[8];
    const float* Wg2 = (const float*)d_in[9];
    const float* bg2 = (const float*)d_in[10];

    char* w = (char*)d_ws;
    _Float16* P16    = (_Float16*)(w + 0);         // [2048][128]        512 KB
    _Float16* xg16   = (_Float16*)(w + 524288);    // [2048][1536]       6.29 MB
    _Float16* g16    = (_Float16*)(w + 6815744);   // [1024][768]
    _Float16* s16    = (_Float16*)(w + 8388608);   // [256][768]
    _Float16* q16    = (_Float16*)(w + 8781824);   // [2048][768]
    _Float16* k16    = (_Float16*)(w + 11927552);  // [1024][768]
    _Float16* vT16   = (_Float16*)(w + 13500416);  // [8][768][128]
    _Float16* Wq16   = (_Float16*)(w + 15073280);  // [768][768]
    _Float16* Wkv16  = (_Float16*)(w + 16252928);  // [1536][768]
    _Float16* Wg116  = (_Float16*)(w + 18612224);  // [768][1536]
    _Float16* Wg2a16 = (_Float16*)(w + 20971520);  // [768][768]
    _Float16* Wg2b16 = (_Float16*)(w + 22151168);  // [768][768]
    float*    bufE   = (float*)(w + 23330816);     // [256][768] fp32
    float*    bufC   = (float*)(w + 24117248);     // gctx fp32 [2048][768]
    float*    bufB   = (float*)(w + 30408704);     // h1 fp32 [2048][768]
    _Float16* h116   = (_Float16*)(w + 36700160);  // [2048][768]
    float* out = (float*)d_out;

    const dim3 blk(256);

    // 1) all f32->f16 conversions in one dispatch
    ConvArgs ca;
    ca.src[0] = x;         ca.dst[0] = xg16;   ca.sstr[0] = 768;  ca.dstr[0] = 1536; ca.rl[0] = 768;
    ca.src[1] = g;         ca.dst[1] = g16;    ca.sstr[1] = 768;  ca.dstr[1] = 768;  ca.rl[1] = 768;
    ca.src[2] = s;         ca.dst[2] = s16;    ca.sstr[2] = 768;  ca.dstr[2] = 768;  ca.rl[2] = 768;
    ca.src[3] = Wq;        ca.dst[3] = Wq16;   ca.sstr[3] = 768;  ca.dstr[3] = 768;  ca.rl[3] = 768;
    ca.src[4] = Wkv;       ca.dst[4] = Wkv16;  ca.sstr[4] = 768;  ca.dstr[4] = 768;  ca.rl[4] = 768;
    ca.src[5] = Wg1;       ca.dst[5] = Wg116;  ca.sstr[5] = 1536; ca.dstr[5] = 1536; ca.rl[5] = 1536;
    ca.src[6] = Wg2;       ca.dst[6] = Wg2a16; ca.sstr[6] = 1536; ca.dstr[6] = 768;  ca.rl[6] = 768;
    ca.src[7] = Wg2 + 768; ca.dst[7] = Wg2b16; ca.sstr[7] = 1536; ca.dstr[7] = 768;  ca.rl[7] = 768;
    ca.cum[0] = 0;      ca.cum[1] = 196608; ca.cum[2] = 294912; ca.cum[3] = 319488;
    ca.cum[4] = 393216; ca.cum[5] = 540672; ca.cum[6] = 688128; ca.cum[7] = 761856;
    ca.cum[8] = 835584;
    conv_multi<<<dim3(3264), blk, 0, stream>>>(ca);

    // 2) q16, {k16,vT16}, E in ONE dispatch (all depend only on conv outputs)
    G3Args ga = {};
    ga.d[0] = { xg16, Wq16,   bq,      (void*)q16,  nullptr,     1536, 768, 0, 12 };  // q: M=2048,N=768
    ga.d[1] = { g16,  Wkv16,  bkv,     (void*)k16,  (void*)vT16, 768,  768, 1, 24 };  // kv: M=1024,N=1536
    ga.d[2] = { s16,  Wg2b16, nullptr, (void*)bufE, nullptr,     768,  768, 2, 12 };  // E: M=256,N=768
    ga.cum[0] = 0; ga.cum[1] = 192; ga.cum[2] = 384; ga.cum[3] = 408;
    gemm3<<<dim3(408), blk, 0, stream>>>(ga);

    // 3) scores + softmax fused -> P16
    attn_scores_sm<<<dim3(4, 8), blk, 0, stream>>>(q16, k16, P16);

    // 4) gctx = P @ v (batched) -> bufC fp32 + xg16 cols 768.. f16
    gemm_f16<<<dim3(12, 2, 8), blk, 0, stream>>>(
        P16, 128, 256L * 128, vT16, 128, 768L * 128, nullptr,
        bufC, 768, 256L * 768, xg16 + 768, 1536, 256L * 1536, 128, 0, nullptr, nullptr);

    // 5) t1 = [x|gctx] @ Wg1^T + bg1, fused gate1 -> bufB (h1) + h116
    gemm_gate1<<<dim3(12, 16), blk, 0, stream>>>(
        xg16, Wg116, bg1, x, bufC, bufB, h116);

    // 6) D = h1 @ Wg2a^T + bg2, fused final combine -> out
    gemm_final<<<dim3(12, 16), blk, 0, stream>>>(
        h116, Wg2a16, bg2, bufE, s, bufB, out);
}

// Round 4
// 314.082 us; speedup vs baseline: 1.1340x; 1.0261x over previous
//
#include <hip/hip_runtime.h>
#include <math.h>

#define Hd 768
#define Bb 8
#define Ll 256
#define Kk 32
#define LG 128

using half4 = __attribute__((ext_vector_type(4))) _Float16;
using half8 = __attribute__((ext_vector_type(8))) _Float16;
using f32x4 = __attribute__((ext_vector_type(4))) float;

__device__ __forceinline__ float sigm(float z) { return 1.f / (1.f + __expf(-z)); }

// ---------------- multi-segment f32 -> f16 conversion (one dispatch) -----------
struct ConvArgs {
    const float* src[8];
    _Float16*    dst[8];
    int cum[9];     // cumulative chunk counts (chunks of 8 elements)
    int sstr[8];    // src row stride (elements)
    int dstr[8];    // dst row stride (elements)
    int rl[8];      // row length (elements, %8==0)
};

__global__ __launch_bounds__(256) void conv_multi(ConvArgs a) {
    int c = blockIdx.x * 256 + threadIdx.x;
    if (c >= a.cum[8]) return;
    int s = 0;
    while (c >= a.cum[s + 1]) ++s;
    const int lc  = c - a.cum[s];
    const unsigned cpr = (unsigned)(a.rl[s] >> 3);
    const unsigned row = (unsigned)lc / cpr;
    const int col = (lc - (int)(row * cpr)) * 8;
    const float* sp = a.src[s] + (size_t)row * a.sstr[s] + col;
    float4 v0 = *(const float4*)sp;
    float4 v1 = *(const float4*)(sp + 4);
    half8 h;
    h[0] = (_Float16)v0.x; h[1] = (_Float16)v0.y; h[2] = (_Float16)v0.z; h[3] = (_Float16)v0.w;
    h[4] = (_Float16)v1.x; h[5] = (_Float16)v1.y; h[6] = (_Float16)v1.z; h[7] = (_Float16)v1.w;
    *(half8*)(a.dst[s] + (size_t)row * a.dstr[s] + col) = h;
}

// ---------------- generic f16 MFMA GEMM (used for gctx) ------------------------
// K-loop uses T14 async-STAGE: loads for step k+1 issue before step k's MFMAs.
__global__ __launch_bounds__(256) void gemm_f16(
    const _Float16* __restrict__ A, int lda, long sA,
    const _Float16* __restrict__ W, int ldw, long sW,
    const float* __restrict__ bias,
    float* __restrict__ C, int ldc, long sC,
    _Float16* __restrict__ C2, int ldc2, long sC2,
    int Kd, int kvsplit,
    _Float16* __restrict__ K16, _Float16* __restrict__ VT16)
{
    __shared__ _Float16 As[128][72];
    __shared__ _Float16 Ws[64][72];

    const int t    = threadIdx.x;
    const int w    = t >> 6;
    const int lane = t & 63;
    const int quad = lane >> 4;
    const int l16  = lane & 15;
    const int bm   = blockIdx.y * 128;
    const int bn   = blockIdx.x * 64;
    const int z    = blockIdx.z;
    A += (size_t)z * sA;
    W += (size_t)z * sW;

    const int sr = t >> 3;
    const int sk = (t & 7) * 8;

    f32x4 acc[2][4] = {};

    half8 av[4], wv[2];
    #pragma unroll
    for (int i = 0; i < 4; ++i)
        av[i] = *(const half8*)(A + (size_t)(bm + i * 32 + sr) * lda + sk);
    #pragma unroll
    for (int i = 0; i < 2; ++i)
        wv[i] = *(const half8*)(W + (size_t)(bn + i * 32 + sr) * ldw + sk);

    for (int k0 = 0; k0 < Kd; k0 += 64) {
        __syncthreads();
        #pragma unroll
        for (int i = 0; i < 4; ++i) *(half8*)&As[i * 32 + sr][sk] = av[i];
        #pragma unroll
        for (int i = 0; i < 2; ++i) *(half8*)&Ws[i * 32 + sr][sk] = wv[i];
        __syncthreads();
        if (k0 + 64 < Kd) {
            #pragma unroll
            for (int i = 0; i < 4; ++i)
                av[i] = *(const half8*)(A + (size_t)(bm + i * 32 + sr) * lda + k0 + 64 + sk);
            #pragma unroll
            for (int i = 0; i < 2; ++i)
                wv[i] = *(const half8*)(W + (size_t)(bn + i * 32 + sr) * ldw + k0 + 64 + sk);
        }
        __builtin_amdgcn_sched_barrier(0);   // keep next-tile loads above MFMA phase
        #pragma unroll
        for (int kk = 0; kk < 2; ++kk) {
            half8 af[2], bf[4];
            af[0] = *(const half8*)&As[w * 32 + l16][kk * 32 + quad * 8];
            af[1] = *(const half8*)&As[w * 32 + 16 + l16][kk * 32 + quad * 8];
            #pragma unroll
            for (int j = 0; j < 4; ++j)
                bf[j] = *(const half8*)&Ws[j * 16 + l16][kk * 32 + quad * 8];
            #pragma unroll
            for (int rt = 0; rt < 2; ++rt)
                #pragma unroll
                for (int j = 0; j < 4; ++j)
                    acc[rt][j] = __builtin_amdgcn_mfma_f32_16x16x32_f16(
                        af[rt], bf[j], acc[rt][j], 0, 0, 0);
        }
    }

    #pragma unroll
    for (int rt = 0; rt < 2; ++rt) {
        #pragma unroll
        for (int j = 0; j < 4; ++j) {
            const int col  = bn + j * 16 + l16;
            const int row0 = bm + w * 32 + rt * 16 + quad * 4;
            const float bv = bias ? bias[col] : 0.f;
            if (kvsplit) {
                if (col < 768) {
                    #pragma unroll
                    for (int r = 0; r < 4; ++r)
                        K16[(size_t)(row0 + r) * 768 + col] = (_Float16)(acc[rt][j][r] + bv);
                } else {
                    const int b = row0 >> 7, h = col - 768, m0 = row0 & 127;
                    half4 hv;
                    #pragma unroll
                    for (int r = 0; r < 4; ++r) hv[r] = (_Float16)(acc[rt][j][r] + bv);
                    *(half4*)(VT16 + ((size_t)(b * 768 + h)) * 128 + m0) = hv;
                }
            } else {
                #pragma unroll
                for (int r = 0; r < 4; ++r) {
                    const float v = acc[rt][j][r] + bv;
                    const size_t rr = (size_t)(row0 + r);
                    if (C)  C[(size_t)z * sC + rr * ldc + col] = v;
                    if (C2) C2[(size_t)z * sC2 + rr * ldc2 + col] = (_Float16)v;
                }
            }
        }
    }
}

// ---------------- merged 3-way GEMM: q, kv, E in one dispatch ------------------
struct G3Desc {
    const _Float16* A;
    const _Float16* W;
    const float* bias;
    void* o0;
    void* o1;
    int lda, ldw, mode, nbx;   // mode 0: f16 out (ld 768); 1: kvsplit; 2: f32 out (ld 768)
};
struct G3Args { G3Desc d[3]; int cum[4]; };

__global__ __launch_bounds__(256) void gemm3(G3Args ga) {
    __shared__ _Float16 As[128][72];
    __shared__ _Float16 Ws[64][72];

    const int t    = threadIdx.x;
    const int w    = t >> 6;
    const int lane = t & 63;
    const int quad = lane >> 4;
    const int l16  = lane & 15;

    int s = 0;
    const int bid = blockIdx.x;
    while (bid >= ga.cum[s + 1]) ++s;
    const int local = bid - ga.cum[s];
    const int nbx   = ga.d[s].nbx;
    const int by    = local / nbx;
    const int bx    = local - by * nbx;
    const int bm    = by * 128;
    const int bn    = bx * 64;
    const _Float16* A = ga.d[s].A;
    const _Float16* W = ga.d[s].W;
    const int lda = ga.d[s].lda;
    const int ldw = ga.d[s].ldw;

    const int sr = t >> 3;
    const int sk = (t & 7) * 8;

    f32x4 acc[2][4] = {};

    half8 av[4], wv[2];
    #pragma unroll
    for (int i = 0; i < 4; ++i)
        av[i] = *(const half8*)(A + (size_t)(bm + i * 32 + sr) * lda + sk);
    #pragma unroll
    for (int i = 0; i < 2; ++i)
        wv[i] = *(const half8*)(W + (size_t)(bn + i * 32 + sr) * ldw + sk);

    for (int k0 = 0; k0 < 768; k0 += 64) {
        __syncthreads();
        #pragma unroll
        for (int i = 0; i < 4; ++i) *(half8*)&As[i * 32 + sr][sk] = av[i];
        #pragma unroll
        for (int i = 0; i < 2; ++i) *(half8*)&Ws[i * 32 + sr][sk] = wv[i];
        __syncthreads();
        if (k0 + 64 < 768) {
            #pragma unroll
            for (int i = 0; i < 4; ++i)
                av[i] = *(const half8*)(A + (size_t)(bm + i * 32 + sr) * lda + k0 + 64 + sk);
            #pragma unroll
            for (int i = 0; i < 2; ++i)
                wv[i] = *(const half8*)(W + (size_t)(bn + i * 32 + sr) * ldw + k0 + 64 + sk);
        }
        __builtin_amdgcn_sched_barrier(0);
        #pragma unroll
        for (int kk = 0; kk < 2; ++kk) {
            half8 af[2], bf[4];
            af[0] = *(const half8*)&As[w * 32 + l16][kk * 32 + quad * 8];
            af[1] = *(const half8*)&As[w * 32 + 16 + l16][kk * 32 + quad * 8];
            #pragma unroll
            for (int j = 0; j < 4; ++j)
                bf[j] = *(const half8*)&Ws[j * 16 + l16][kk * 32 + quad * 8];
            #pragma unroll
            for (int rt = 0; rt < 2; ++rt)
                #pragma unroll
                for (int j = 0; j < 4; ++j)
                    acc[rt][j] = __builtin_amdgcn_mfma_f32_16x16x32_f16(
                        af[rt], bf[j], acc[rt][j], 0, 0, 0);
        }
    }

    const int mode = ga.d[s].mode;
    const float* bias = ga.d[s].bias;
    #pragma unroll
    for (int rt = 0; rt < 2; ++rt) {
        #pragma unroll
        for (int j = 0; j < 4; ++j) {
            const int col  = bn + j * 16 + l16;
            const int row0 = bm + w * 32 + rt * 16 + quad * 4;
            const float bv = bias ? bias[col] : 0.f;
            if (mode == 0) {
                _Float16* C2 = (_Float16*)ga.d[s].o0;
                #pragma unroll
                for (int r = 0; r < 4; ++r)
                    C2[(size_t)(row0 + r) * 768 + col] = (_Float16)(acc[rt][j][r] + bv);
            } else if (mode == 1) {
                _Float16* K16  = (_Float16*)ga.d[s].o0;
                _Float16* VT16 = (_Float16*)ga.d[s].o1;
                if (col < 768) {
                    #pragma unroll
                    for (int r = 0; r < 4; ++r)
                        K16[(size_t)(row0 + r) * 768 + col] = (_Float16)(acc[rt][j][r] + bv);
                } else {
                    const int b = row0 >> 7, h = col - 768, m0 = row0 & 127;
                    half4 hv;
                    #pragma unroll
                    for (int r = 0; r < 4; ++r) hv[r] = (_Float16)(acc[rt][j][r] + bv);
                    *(half4*)(VT16 + ((size_t)(b * 768 + h)) * 128 + m0) = hv;
                }
            } else {
                float* C = (float*)ga.d[s].o0;
                #pragma unroll
                for (int r = 0; r < 4; ++r)
                    C[(size_t)(row0 + r) * 768 + col] = acc[rt][j][r] + bv;
            }
        }
    }
}

// ---------------- fused scores + softmax ---------------------------------------
// block: 64 q-rows x all 128 keys of one batch. grid (4, 8).
__global__ __launch_bounds__(256) void attn_scores_sm(
    const _Float16* __restrict__ Q, const _Float16* __restrict__ Kt,
    _Float16* __restrict__ P)
{
    __shared__ _Float16 As[64][72];
    __shared__ _Float16 Ws[128][72];

    const int t    = threadIdx.x;
    const int w    = t >> 6;
    const int lane = t & 63;
    const int quad = lane >> 4;
    const int l16  = lane & 15;
    const int z    = blockIdx.y;
    const int bm   = blockIdx.x * 64;
    const _Float16* A = Q  + (size_t)z * 256 * 768 + (size_t)bm * 768;
    const _Float16* W = Kt + (size_t)z * 128 * 768;

    const int sr = t >> 3;
    const int sk = (t & 7) * 8;

    f32x4 acc[8] = {};

    half8 av[2], wv[4];
    #pragma unroll
    for (int i = 0; i < 2; ++i)
        av[i] = *(const half8*)(A + (size_t)(i * 32 + sr) * 768 + sk);
    #pragma unroll
    for (int i = 0; i < 4; ++i)
        wv[i] = *(const half8*)(W + (size_t)(i * 32 + sr) * 768 + sk);

    for (int k0 = 0; k0 < 768; k0 += 64) {
        __syncthreads();
        #pragma unroll
        for (int i = 0; i < 2; ++i) *(half8*)&As[i * 32 + sr][sk] = av[i];
        #pragma unroll
        for (int i = 0; i < 4; ++i) *(half8*)&Ws[i * 32 + sr][sk] = wv[i];
        __syncthreads();
        if (k0 + 64 < 768) {
            #pragma unroll
            for (int i = 0; i < 2; ++i)
                av[i] = *(const half8*)(A + (size_t)(i * 32 + sr) * 768 + k0 + 64 + sk);
            #pragma unroll
            for (int i = 0; i < 4; ++i)
                wv[i] = *(const half8*)(W + (size_t)(i * 32 + sr) * 768 + k0 + 64 + sk);
        }
        __builtin_amdgcn_sched_barrier(0);
        #pragma unroll
        for (int kk = 0; kk < 2; ++kk) {
            half8 af = *(const half8*)&As[w * 16 + l16][kk * 32 + quad * 8];
            #pragma unroll
            for (int j = 0; j < 8; ++j) {
                half8 bf = *(const half8*)&Ws[j * 16 + l16][kk * 32 + quad * 8];
                acc[j] = __builtin_amdgcn_mfma_f32_16x16x32_f16(af, bf, acc[j], 0, 0, 0);
            }
        }
    }

    const float scale = 0.03608439182435161f;   // 1/sqrt(768)
    #pragma unroll
    for (int r = 0; r < 4; ++r) {
        float v[8];
        float mx = -1e30f;
        #pragma unroll
        for (int j = 0; j < 8; ++j) { v[j] = acc[j][r] * scale; mx = fmaxf(mx, v[j]); }
        #pragma unroll
        for (int off = 8; off; off >>= 1) mx = fmaxf(mx, __shfl_xor(mx, off, 16));
        float sum = 0.f;
        #pragma unroll
        for (int j = 0; j < 8; ++j) { v[j] = __expf(v[j] - mx); sum += v[j]; }
        #pragma unroll
        for (int off = 8; off; off >>= 1) sum += __shfl_xor(sum, off, 16);
        const float inv = 1.f / sum;
        const int row = bm + w * 16 + quad * 4 + r;
        _Float16* Pr = P + (size_t)z * 256 * 128 + (size_t)row * 128;
        #pragma unroll
        for (int j = 0; j < 8; ++j) Pr[j * 16 + l16] = (_Float16)(v[j] * inv);
    }
}

// ---------------- t1 GEMM with fused gate1 epilogue ----------------------------
__global__ __launch_bounds__(256) void gemm_gate1(
    const _Float16* __restrict__ A,   // xg16 [2048][1536]
    const _Float16* __restrict__ W,   // Wg116 [768][1536]
    const float* __restrict__ bias,   // bg1
    const float* __restrict__ X,      // x fp32
    const float* __restrict__ GC,     // gctx fp32
    float* __restrict__ H1,
    _Float16* __restrict__ H16)
{
    __shared__ _Float16 As[128][72];
    __shared__ _Float16 Ws[64][72];

    const int t    = threadIdx.x;
    const int w    = t >> 6;
    const int lane = t & 63;
    const int quad = lane >> 4;
    const int l16  = lane & 15;
    const int bm   = blockIdx.y * 128;
    const int bn   = blockIdx.x * 64;

    const int sr = t >> 3;
    const int sk = (t & 7) * 8;

    f32x4 acc[2][4] = {};

    half8 av[4], wv[2];
    #pragma unroll
    for (int i = 0; i < 4; ++i)
        av[i] = *(const half8*)(A + (size_t)(bm + i * 32 + sr) * 1536 + sk);
    #pragma unroll
    for (int i = 0; i < 2; ++i)
        wv[i] = *(const half8*)(W + (size_t)(bn + i * 32 + sr) * 1536 + sk);

    for (int k0 = 0; k0 < 1536; k0 += 64) {
        __syncthreads();
        #pragma unroll
        for (int i = 0; i < 4; ++i) *(half8*)&As[i * 32 + sr][sk] = av[i];
        #pragma unroll
        for (int i = 0; i < 2; ++i) *(half8*)&Ws[i * 32 + sr][sk] = wv[i];
        __syncthreads();
        if (k0 + 64 < 1536) {
            #pragma unroll
            for (int i = 0; i < 4; ++i)
                av[i] = *(const half8*)(A + (size_t)(bm + i * 32 + sr) * 1536 + k0 + 64 + sk);
            #pragma unroll
            for (int i = 0; i < 2; ++i)
                wv[i] = *(const half8*)(W + (size_t)(bn + i * 32 + sr) * 1536 + k0 + 64 + sk);
        }
        __builtin_amdgcn_sched_barrier(0);
        #pragma unroll
        for (int kk = 0; kk < 2; ++kk) {
            half8 af[2], bf[4];
            af[0] = *(const half8*)&As[w * 32 + l16][kk * 32 + quad * 8];
            af[1] = *(const half8*)&As[w * 32 + 16 + l16][kk * 32 + quad * 8];
            #pragma unroll
            for (int j = 0; j < 4; ++j)
                bf[j] = *(const half8*)&Ws[j * 16 + l16][kk * 32 + quad * 8];
            #pragma unroll
            for (int rt = 0; rt < 2; ++rt)
                #pragma unroll
                for (int j = 0; j < 4; ++j)
                    acc[rt][j] = __builtin_amdgcn_mfma_f32_16x16x32_f16(
                        af[rt], bf[j], acc[rt][j], 0, 0, 0);
        }
    }

    #pragma unroll
    for (int rt = 0; rt < 2; ++rt) {
        #pragma unroll
        for (int j = 0; j < 4; ++j) {
            const int col  = bn + j * 16 + l16;
            const int row0 = bm + w * 32 + rt * 16 + quad * 4;
            const float bv = bias[col];
            #pragma unroll
            for (int r = 0; r < 4; ++r) {
                const size_t off = (size_t)(row0 + r) * 768 + col;
                const float g = sigm(acc[rt][j][r] + bv);
                const float o = g * X[off] + (1.f - g) * GC[off];
                H1[off]  = o;
                H16[off] = (_Float16)o;
            }
        }
    }
}

// ---------------- D GEMM with fused final_combine epilogue ---------------------
// out[b,l,k,h] = sig(D[b,l,h] + E[b,k,h]) * h1[b,l,h] + (1-sig) * s[b,k,h]
__global__ __launch_bounds__(256) void gemm_final(
    const _Float16* __restrict__ A,   // h116 [2048][768]
    const _Float16* __restrict__ W,   // Wg2a16 [768][768]
    const float* __restrict__ bias,   // bg2
    const float* __restrict__ Ebuf,   // [256][768] fp32
    const float* __restrict__ Sbuf,   // s fp32 [256][768]
    const float* __restrict__ H1,     // h1 fp32 [2048][768]
    float* __restrict__ out)
{
    __shared__ union {
        struct { _Float16 As[128][72]; _Float16 Ws[64][72]; } a;
        float Ds[128][76];            // 76: float4-aligned, 2-way-max bank pattern
    } u;
    __shared__ float Es[32][64];
    __shared__ float Ss[32][64];

    const int t    = threadIdx.x;
    const int w    = t >> 6;
    const int lane = t & 63;
    const int quad = lane >> 4;
    const int l16  = lane & 15;
    const int bm   = blockIdx.y * 128;
    const int bn   = blockIdx.x * 64;
    const int bK   = (bm >> 8) * 32;  // batch * 32 row base into E/s

    const int sr = t >> 3;
    const int sk = (t & 7) * 8;

    // stage E and s slices (ready since gemm3 / input)
    #pragma unroll
    for (int i = 0; i < 2; ++i) {
        const int idx = t + i * 256;
        const int k = idx >> 4, c = (idx & 15) * 4;
        *(float4*)&Es[k][c] = *(const float4*)(Ebuf + (size_t)(bK + k) * 768 + bn + c);
        *(float4*)&Ss[k][c] = *(const float4*)(Sbuf + (size_t)(bK + k) * 768 + bn + c);
    }

    f32x4 acc[2][4] = {};

    half8 av[4], wv[2];
    #pragma unroll
    for (int i = 0; i < 4; ++i)
        av[i] = *(const half8*)(A + (size_t)(bm + i * 32 + sr) * 768 + sk);
    #pragma unroll
    for (int i = 0; i < 2; ++i)
        wv[i] = *(const half8*)(W + (size_t)(bn + i * 32 + sr) * 768 + sk);

    for (int k0 = 0; k0 < 768; k0 += 64) {
        __syncthreads();
        #pragma unroll
        for (int i = 0; i < 4; ++i) *(half8*)&u.a.As[i * 32 + sr][sk] = av[i];
        #pragma unroll
        for (int i = 0; i < 2; ++i) *(half8*)&u.a.Ws[i * 32 + sr][sk] = wv[i];
        __syncthreads();
        if (k0 + 64 < 768) {
            #pragma unroll
            for (int i = 0; i < 4; ++i)
                av[i] = *(const half8*)(A + (size_t)(bm + i * 32 + sr) * 768 + k0 + 64 + sk);
            #pragma unroll
            for (int i = 0; i < 2; ++i)
                wv[i] = *(const half8*)(W + (size_t)(bn + i * 32 + sr) * 768 + k0 + 64 + sk);
        }
        __builtin_amdgcn_sched_barrier(0);
        #pragma unroll
        for (int kk = 0; kk < 2; ++kk) {
            half8 af[2], bf[4];
            af[0] = *(const half8*)&u.a.As[w * 32 + l16][kk * 32 + quad * 8];
            af[1] = *(const half8*)&u.a.As[w * 32 + 16 + l16][kk * 32 + quad * 8];
            #pragma unroll
            for (int j = 0; j < 4; ++j)
                bf[j] = *(const half8*)&u.a.Ws[j * 16 + l16][kk * 32 + quad * 8];
            #pragma unroll
            for (int rt = 0; rt < 2; ++rt)
                #pragma unroll
                for (int j = 0; j < 4; ++j)
                    acc[rt][j] = __builtin_amdgcn_mfma_f32_16x16x32_f16(
                        af[rt], bf[j], acc[rt][j], 0, 0, 0);
        }
    }

    __syncthreads();   // done reading As/Ws — union memory becomes Ds
    #pragma unroll
    for (int rt = 0; rt < 2; ++rt) {
        #pragma unroll
        for (int j = 0; j < 4; ++j) {
            const int col = j * 16 + l16;
            const float bv = bias[bn + col];
            #pragma unroll
            for (int r = 0; r < 4; ++r)
                u.Ds[w * 32 + rt * 16 + quad * 4 + r][col] = acc[rt][j][r] + bv;
        }
    }
    __syncthreads();

    // re-layout: thread owns 8 consecutive rows x one float4 column group
    const int c  = (t & 15) * 4;
    const int r0 = (t >> 4) * 8;
    float4 d[8], h[8];
    #pragma unroll
    for (int rr = 0; rr < 8; ++rr) {
        d[rr] = *(const float4*)&u.Ds[r0 + rr][c];
        h[rr] = *(const float4*)(H1 + (size_t)(bm + r0 + rr) * 768 + bn + c);
    }
    float* ob = out + (size_t)(bm + r0) * 32 * 768 + bn + c;
    for (int k = 0; k < 32; ++k) {
        const float4 e  = *(const float4*)&Es[k][c];
        const float4 sv = *(const float4*)&Ss[k][c];
        #pragma unroll
        for (int rr = 0; rr < 8; ++rr) {
            float4 o; float g;
            g = sigm(d[rr].x + e.x); o.x = g * h[rr].x + (1.f - g) * sv.x;
            g = sigm(d[rr].y + e.y); o.y = g * h[rr].y + (1.f - g) * sv.y;
            g = sigm(d[rr].z + e.z); o.z = g * h[rr].z + (1.f - g) * sv.z;
            g = sigm(d[rr].w + e.w); o.w = g * h[rr].w + (1.f - g) * sv.w;
            *(float4*)(ob + (size_t)(rr * 32 + k) * 768) = o;
        }
    }
}

extern "C" void kernel_launch(void* const* d_in, const int* in_sizes, int n_in,
                              void* d_out, int out_size, void* d_ws, size_t ws_size,
                              hipStream_t stream) {
    const float* x   = (const float*)d_in[0];
    const float* s   = (const float*)d_in[1];
    const float* g   = (const float*)d_in[2];
    const float* Wq  = (const float*)d_in[3];
    const float* bq  = (const float*)d_in[4];
    const float* Wkv = (const float*)d_in[5];
    const float* bkv = (const float*)d_in[6];
    const float* Wg1 = (const float*)d_in[7];
    const float* bg1 = (const float*)d_in[8];
    const float* Wg2 = (const float*)d_in[9];
    const float* bg2 = (const float*)d_in[10];

    char* w = (char*)d_ws;
    _Float16* P16    = (_Float16*)(w + 0);         // [2048][128]        512 KB
    _Float16* xg16   = (_Float16*)(w + 524288);    // [2048][1536]       6.29 MB
    _Float16* g16    = (_Float16*)(w + 6815744);   // [1024][768]
    _Float16* s16    = (_Float16*)(w + 8388608);   // [256][768]
    _Float16* q16    = (_Float16*)(w + 8781824);   // [2048][768]
    _Float16* k16    = (_Float16*)(w + 11927552);  // [1024][768]
    _Float16* vT16   = (_Float16*)(w + 13500416);  // [8][768][128]
    _Float16* Wq16   = (_Float16*)(w + 15073280);  // [768][768]
    _Float16* Wkv16  = (_Float16*)(w + 16252928);  // [1536][768]
    _Float16* Wg116  = (_Float16*)(w + 18612224);  // [768][1536]
    _Float16* Wg2a16 = (_Float16*)(w + 20971520);  // [768][768]
    _Float16* Wg2b16 = (_Float16*)(w + 22151168);  // [768][768]
    float*    bufE   = (float*)(w + 23330816);     // [256][768] fp32
    float*    bufC   = (float*)(w + 24117248);     // gctx fp32 [2048][768]
    float*    bufB   = (float*)(w + 30408704);     // h1 fp32 [2048][768]
    _Float16* h116   = (_Float16*)(w + 36700160);  // [2048][768]
    float* out = (float*)d_out;

    const dim3 blk(256);

    // 1) all f32->f16 conversions in one dispatch
    ConvArgs ca;
    ca.src[0] = x;         ca.dst[0] = xg16;   ca.sstr[0] = 768;  ca.dstr[0] = 1536; ca.rl[0] = 768;
    ca.src[1] = g;         ca.dst[1] = g16;    ca.sstr[1] = 768;  ca.dstr[1] = 768;  ca.rl[1] = 768;
    ca.src[2] = s;         ca.dst[2] = s16;    ca.sstr[2] = 768;  ca.dstr[2] = 768;  ca.rl[2] = 768;
    ca.src[3] = Wq;        ca.dst[3] = Wq16;   ca.sstr[3] = 768;  ca.dstr[3] = 768;  ca.rl[3] = 768;
    ca.src[4] = Wkv;       ca.dst[4] = Wkv16;  ca.sstr[4] = 768;  ca.dstr[4] = 768;  ca.rl[4] = 768;
    ca.src[5] = Wg1;       ca.dst[5] = Wg116;  ca.sstr[5] = 1536; ca.dstr[5] = 1536; ca.rl[5] = 1536;
    ca.src[6] = Wg2;       ca.dst[6] = Wg2a16; ca.sstr[6] = 1536; ca.dstr[6] = 768;  ca.rl[6] = 768;
    ca.src[7] = Wg2 + 768; ca.dst[7] = Wg2b16; ca.sstr[7] = 1536; ca.dstr[7] = 768;  ca.rl[7] = 768;
    ca.cum[0] = 0;      ca.cum[1] = 196608; ca.cum[2] = 294912; ca.cum[3] = 319488;
    ca.cum[4] = 393216; ca.cum[5] = 540672; ca.cum[6] = 688128; ca.cum[7] = 761856;
    ca.cum[8] = 835584;
    conv_multi<<<dim3(3264), blk, 0, stream>>>(ca);

    // 2) q16, {k16,vT16}, E in ONE dispatch (all depend only on conv outputs)
    G3Args ga = {};
    ga.d[0] = { xg16, Wq16,   bq,      (void*)q16,  nullptr,     1536, 768, 0, 12 };  // q: M=2048,N=768
    ga.d[1] = { g16,  Wkv16,  bkv,     (void*)k16,  (void*)vT16, 768,  768, 1, 24 };  // kv: M=1024,N=1536
    ga.d[2] = { s16,  Wg2b16, nullptr, (void*)bufE, nullptr,     768,  768, 2, 12 };  // E: M=256,N=768
    ga.cum[0] = 0; ga.cum[1] = 192; ga.cum[2] = 384; ga.cum[3] = 408;
    gemm3<<<dim3(408), blk, 0, stream>>>(ga);

    // 3) scores + softmax fused -> P16
    attn_scores_sm<<<dim3(4, 8), blk, 0, stream>>>(q16, k16, P16);

    // 4) gctx = P @ v (batched) -> bufC fp32 + xg16 cols 768.. f16
    gemm_f16<<<dim3(12, 2, 8), blk, 0, stream>>>(
        P16, 128, 256L * 128, vT16, 128, 768L * 128, nullptr,
        bufC, 768, 256L * 768, xg16 + 768, 1536, 256L * 1536, 128, 0, nullptr, nullptr);

    // 5) t1 = [x|gctx] @ Wg1^T + bg1, fused gate1 -> bufB (h1) + h116
    gemm_gate1<<<dim3(12, 16), blk, 0, stream>>>(
        xg16, Wg116, bg1, x, bufC, bufB, h116);

    // 6) D = h1 @ Wg2a^T + bg2, fused final combine -> out
    gemm_final<<<dim3(12, 16), blk, 0, stream>>>(
        h116, Wg2a16, bg2, bufE, s, bufB, out);
}

// Round 5
// 311.364 us; speedup vs baseline: 1.1439x; 1.0087x over previous
//
#include <hip/hip_runtime.h>
#include <math.h>

#define Hd 768
#define Bb 8
#define Ll 256
#define Kk 32
#define LG 128

using half4 = __attribute__((ext_vector_type(4))) _Float16;
using half8 = __attribute__((ext_vector_type(8))) _Float16;
using f32x4 = __attribute__((ext_vector_type(4))) float;

__device__ __forceinline__ float sigm(float z) { return 1.f / (1.f + __expf(-z)); }

// ---------------- multi-segment f32 -> f16 conversion (one dispatch) -----------
struct ConvArgs {
    const float* src[8];
    _Float16*    dst[8];
    int cum[9];     // cumulative chunk counts (chunks of 8 elements)
    int sstr[8];    // src row stride (elements)
    int dstr[8];    // dst row stride (elements)
    int rl[8];      // row length (elements, %8==0)
};

__global__ __launch_bounds__(256) void conv_multi(ConvArgs a) {
    int c = blockIdx.x * 256 + threadIdx.x;
    if (c >= a.cum[8]) return;
    int s = 0;
    while (c >= a.cum[s + 1]) ++s;
    const int lc  = c - a.cum[s];
    const unsigned cpr = (unsigned)(a.rl[s] >> 3);
    const unsigned row = (unsigned)lc / cpr;
    const int col = (lc - (int)(row * cpr)) * 8;
    const float* sp = a.src[s] + (size_t)row * a.sstr[s] + col;
    float4 v0 = *(const float4*)sp;
    float4 v1 = *(const float4*)(sp + 4);
    half8 h;
    h[0] = (_Float16)v0.x; h[1] = (_Float16)v0.y; h[2] = (_Float16)v0.z; h[3] = (_Float16)v0.w;
    h[4] = (_Float16)v1.x; h[5] = (_Float16)v1.y; h[6] = (_Float16)v1.z; h[7] = (_Float16)v1.w;
    *(half8*)(a.dst[s] + (size_t)row * a.dstr[s] + col) = h;
}

// ======================= 64x64-tile GEMM family ================================
// Block: 64 rows x 64 cols, 4 waves; wave w = rows [w*16, w*16+16) x all 64 cols.
// acc[4] f32x4. Grid doubles vs 128x64 tiles -> 1.5-3 blocks/CU (occupancy fix).
// T14 prefetch: next K-tile's global loads issue before this tile's MFMA phase.

// ---------------- merged 3-way GEMM: q, kv, E in one dispatch ------------------
struct G3Desc {
    const _Float16* A;
    const _Float16* W;
    const float* bias;
    void* o0;
    void* o1;
    int lda, ldw, mode, nbx;   // mode 0: f16 out (ld 768); 1: kvsplit; 2: f32 out (ld 768)
};
struct G3Args { G3Desc d[3]; int cum[4]; };

__global__ __launch_bounds__(256) void gemm3(G3Args ga) {
    __shared__ _Float16 As[64][72];
    __shared__ _Float16 Ws[64][72];

    const int t    = threadIdx.x;
    const int w    = t >> 6;
    const int lane = t & 63;
    const int quad = lane >> 4;
    const int l16  = lane & 15;

    int s = 0;
    const int bid = blockIdx.x;
    while (bid >= ga.cum[s + 1]) ++s;
    const int local = bid - ga.cum[s];
    const int nbx   = ga.d[s].nbx;
    const int by    = local / nbx;
    const int bx    = local - by * nbx;
    const int bm    = by * 64;
    const int bn    = bx * 64;
    const _Float16* A = ga.d[s].A;
    const _Float16* W = ga.d[s].W;
    const int lda = ga.d[s].lda;
    const int ldw = ga.d[s].ldw;

    const int sr = t >> 3;          // 0..31
    const int sk = (t & 7) * 8;     // 0..56

    f32x4 acc[4] = {};

    half8 av[2], wv[2];
    #pragma unroll
    for (int i = 0; i < 2; ++i) {
        av[i] = *(const half8*)(A + (size_t)(bm + i * 32 + sr) * lda + sk);
        wv[i] = *(const half8*)(W + (size_t)(bn + i * 32 + sr) * ldw + sk);
    }

    for (int k0 = 0; k0 < 768; k0 += 64) {
        __syncthreads();
        #pragma unroll
        for (int i = 0; i < 2; ++i) {
            *(half8*)&As[i * 32 + sr][sk] = av[i];
            *(half8*)&Ws[i * 32 + sr][sk] = wv[i];
        }
        __syncthreads();
        if (k0 + 64 < 768) {
            #pragma unroll
            for (int i = 0; i < 2; ++i) {
                av[i] = *(const half8*)(A + (size_t)(bm + i * 32 + sr) * lda + k0 + 64 + sk);
                wv[i] = *(const half8*)(W + (size_t)(bn + i * 32 + sr) * ldw + k0 + 64 + sk);
            }
        }
        __builtin_amdgcn_sched_barrier(0);
        #pragma unroll
        for (int kk = 0; kk < 2; ++kk) {
            half8 af = *(const half8*)&As[w * 16 + l16][kk * 32 + quad * 8];
            #pragma unroll
            for (int j = 0; j < 4; ++j) {
                half8 bf = *(const half8*)&Ws[j * 16 + l16][kk * 32 + quad * 8];
                acc[j] = __builtin_amdgcn_mfma_f32_16x16x32_f16(af, bf, acc[j], 0, 0, 0);
            }
        }
    }

    const int mode = ga.d[s].mode;
    const float* bias = ga.d[s].bias;
    #pragma unroll
    for (int j = 0; j < 4; ++j) {
        const int col  = bn + j * 16 + l16;
        const int row0 = bm + w * 16 + quad * 4;
        const float bv = bias ? bias[col] : 0.f;
        if (mode == 0) {
            _Float16* C2 = (_Float16*)ga.d[s].o0;
            #pragma unroll
            for (int r = 0; r < 4; ++r)
                C2[(size_t)(row0 + r) * 768 + col] = (_Float16)(acc[j][r] + bv);
        } else if (mode == 1) {
            _Float16* K16  = (_Float16*)ga.d[s].o0;
            _Float16* VT16 = (_Float16*)ga.d[s].o1;
            if (col < 768) {
                #pragma unroll
                for (int r = 0; r < 4; ++r)
                    K16[(size_t)(row0 + r) * 768 + col] = (_Float16)(acc[j][r] + bv);
            } else {
                const int b = row0 >> 7, h = col - 768, m0 = row0 & 127;
                half4 hv;
                #pragma unroll
                for (int r = 0; r < 4; ++r) hv[r] = (_Float16)(acc[j][r] + bv);
                *(half4*)(VT16 + ((size_t)(b * 768 + h)) * 128 + m0) = hv;
            }
        } else {
            float* C = (float*)ga.d[s].o0;
            #pragma unroll
            for (int r = 0; r < 4; ++r)
                C[(size_t)(row0 + r) * 768 + col] = acc[j][r] + bv;
        }
    }
}

// ---------------- fused scores + softmax ---------------------------------------
// block: 64 q-rows x all 128 keys of one batch. grid (4, 8).
__global__ __launch_bounds__(256) void attn_scores_sm(
    const _Float16* __restrict__ Q, const _Float16* __restrict__ Kt,
    _Float16* __restrict__ P)
{
    __shared__ _Float16 As[64][72];
    __shared__ _Float16 Ws[128][72];

    const int t    = threadIdx.x;
    const int w    = t >> 6;
    const int lane = t & 63;
    const int quad = lane >> 4;
    const int l16  = lane & 15;
    const int z    = blockIdx.y;
    const int bm   = blockIdx.x * 64;
    const _Float16* A = Q  + (size_t)z * 256 * 768 + (size_t)bm * 768;
    const _Float16* W = Kt + (size_t)z * 128 * 768;

    const int sr = t >> 3;
    const int sk = (t & 7) * 8;

    f32x4 acc[8] = {};

    half8 av[2], wv[4];
    #pragma unroll
    for (int i = 0; i < 2; ++i)
        av[i] = *(const half8*)(A + (size_t)(i * 32 + sr) * 768 + sk);
    #pragma unroll
    for (int i = 0; i < 4; ++i)
        wv[i] = *(const half8*)(W + (size_t)(i * 32 + sr) * 768 + sk);

    for (int k0 = 0; k0 < 768; k0 += 64) {
        __syncthreads();
        #pragma unroll
        for (int i = 0; i < 2; ++i) *(half8*)&As[i * 32 + sr][sk] = av[i];
        #pragma unroll
        for (int i = 0; i < 4; ++i) *(half8*)&Ws[i * 32 + sr][sk] = wv[i];
        __syncthreads();
        if (k0 + 64 < 768) {
            #pragma unroll
            for (int i = 0; i < 2; ++i)
                av[i] = *(const half8*)(A + (size_t)(i * 32 + sr) * 768 + k0 + 64 + sk);
            #pragma unroll
            for (int i = 0; i < 4; ++i)
                wv[i] = *(const half8*)(W + (size_t)(i * 32 + sr) * 768 + k0 + 64 + sk);
        }
        __builtin_amdgcn_sched_barrier(0);
        #pragma unroll
        for (int kk = 0; kk < 2; ++kk) {
            half8 af = *(const half8*)&As[w * 16 + l16][kk * 32 + quad * 8];
            #pragma unroll
            for (int j = 0; j < 8; ++j) {
                half8 bf = *(const half8*)&Ws[j * 16 + l16][kk * 32 + quad * 8];
                acc[j] = __builtin_amdgcn_mfma_f32_16x16x32_f16(af, bf, acc[j], 0, 0, 0);
            }
        }
    }

    const float scale = 0.03608439182435161f;   // 1/sqrt(768)
    #pragma unroll
    for (int r = 0; r < 4; ++r) {
        float v[8];
        float mx = -1e30f;
        #pragma unroll
        for (int j = 0; j < 8; ++j) { v[j] = acc[j][r] * scale; mx = fmaxf(mx, v[j]); }
        #pragma unroll
        for (int off = 8; off; off >>= 1) mx = fmaxf(mx, __shfl_xor(mx, off, 16));
        float sum = 0.f;
        #pragma unroll
        for (int j = 0; j < 8; ++j) { v[j] = __expf(v[j] - mx); sum += v[j]; }
        #pragma unroll
        for (int off = 8; off; off >>= 1) sum += __shfl_xor(sum, off, 16);
        const float inv = 1.f / sum;
        const int row = bm + w * 16 + quad * 4 + r;
        _Float16* Pr = P + (size_t)z * 256 * 128 + (size_t)row * 128;
        #pragma unroll
        for (int j = 0; j < 8; ++j) Pr[j * 16 + l16] = (_Float16)(v[j] * inv);
    }
}

// ---------------- gctx GEMM (batched, K=128): C fp32 + C2 f16 ------------------
__global__ __launch_bounds__(256) void gemm_gctx(
    const _Float16* __restrict__ A, int lda, long sA,
    const _Float16* __restrict__ W, int ldw, long sW,
    float* __restrict__ C, int ldc, long sC,
    _Float16* __restrict__ C2, int ldc2, long sC2)
{
    __shared__ _Float16 As[64][72];
    __shared__ _Float16 Ws[64][72];

    const int t    = threadIdx.x;
    const int w    = t >> 6;
    const int lane = t & 63;
    const int quad = lane >> 4;
    const int l16  = lane & 15;
    const int bm   = blockIdx.y * 64;
    const int bn   = blockIdx.x * 64;
    const int z    = blockIdx.z;
    A += (size_t)z * sA;
    W += (size_t)z * sW;

    const int sr = t >> 3;
    const int sk = (t & 7) * 8;

    f32x4 acc[4] = {};

    half8 av[2], wv[2];
    #pragma unroll
    for (int i = 0; i < 2; ++i) {
        av[i] = *(const half8*)(A + (size_t)(bm + i * 32 + sr) * lda + sk);
        wv[i] = *(const half8*)(W + (size_t)(bn + i * 32 + sr) * ldw + sk);
    }

    for (int k0 = 0; k0 < 128; k0 += 64) {
        __syncthreads();
        #pragma unroll
        for (int i = 0; i < 2; ++i) {
            *(half8*)&As[i * 32 + sr][sk] = av[i];
            *(half8*)&Ws[i * 32 + sr][sk] = wv[i];
        }
        __syncthreads();
        if (k0 + 64 < 128) {
            #pragma unroll
            for (int i = 0; i < 2; ++i) {
                av[i] = *(const half8*)(A + (size_t)(bm + i * 32 + sr) * lda + k0 + 64 + sk);
                wv[i] = *(const half8*)(W + (size_t)(bn + i * 32 + sr) * ldw + k0 + 64 + sk);
            }
        }
        __builtin_amdgcn_sched_barrier(0);
        #pragma unroll
        for (int kk = 0; kk < 2; ++kk) {
            half8 af = *(const half8*)&As[w * 16 + l16][kk * 32 + quad * 8];
            #pragma unroll
            for (int j = 0; j < 4; ++j) {
                half8 bf = *(const half8*)&Ws[j * 16 + l16][kk * 32 + quad * 8];
                acc[j] = __builtin_amdgcn_mfma_f32_16x16x32_f16(af, bf, acc[j], 0, 0, 0);
            }
        }
    }

    #pragma unroll
    for (int j = 0; j < 4; ++j) {
        const int col  = bn + j * 16 + l16;
        const int row0 = bm + w * 16 + quad * 4;
        #pragma unroll
        for (int r = 0; r < 4; ++r) {
            const float v = acc[j][r];
            const size_t rr = (size_t)(row0 + r);
            C[(size_t)z * sC + rr * ldc + col] = v;
            C2[(size_t)z * sC2 + rr * ldc2 + col] = (_Float16)v;
        }
    }
}

// ---------------- t1 GEMM with fused gate1 epilogue ----------------------------
__global__ __launch_bounds__(256) void gemm_gate1(
    const _Float16* __restrict__ A,   // xg16 [2048][1536]
    const _Float16* __restrict__ W,   // Wg116 [768][1536]
    const float* __restrict__ bias,   // bg1
    const float* __restrict__ X,      // x fp32
    const float* __restrict__ GC,     // gctx fp32
    float* __restrict__ H1,
    _Float16* __restrict__ H16)
{
    __shared__ _Float16 As[64][72];
    __shared__ _Float16 Ws[64][72];

    const int t    = threadIdx.x;
    const int w    = t >> 6;
    const int lane = t & 63;
    const int quad = lane >> 4;
    const int l16  = lane & 15;
    const int bm   = blockIdx.y * 64;
    const int bn   = blockIdx.x * 64;

    const int sr = t >> 3;
    const int sk = (t & 7) * 8;

    f32x4 acc[4] = {};

    half8 av[2], wv[2];
    #pragma unroll
    for (int i = 0; i < 2; ++i) {
        av[i] = *(const half8*)(A + (size_t)(bm + i * 32 + sr) * 1536 + sk);
        wv[i] = *(const half8*)(W + (size_t)(bn + i * 32 + sr) * 1536 + sk);
    }

    for (int k0 = 0; k0 < 1536; k0 += 64) {
        __syncthreads();
        #pragma unroll
        for (int i = 0; i < 2; ++i) {
            *(half8*)&As[i * 32 + sr][sk] = av[i];
            *(half8*)&Ws[i * 32 + sr][sk] = wv[i];
        }
        __syncthreads();
        if (k0 + 64 < 1536) {
            #pragma unroll
            for (int i = 0; i < 2; ++i) {
                av[i] = *(const half8*)(A + (size_t)(bm + i * 32 + sr) * 1536 + k0 + 64 + sk);
                wv[i] = *(const half8*)(W + (size_t)(bn + i * 32 + sr) * 1536 + k0 + 64 + sk);
            }
        }
        __builtin_amdgcn_sched_barrier(0);
        #pragma unroll
        for (int kk = 0; kk < 2; ++kk) {
            half8 af = *(const half8*)&As[w * 16 + l16][kk * 32 + quad * 8];
            #pragma unroll
            for (int j = 0; j < 4; ++j) {
                half8 bf = *(const half8*)&Ws[j * 16 + l16][kk * 32 + quad * 8];
                acc[j] = __builtin_amdgcn_mfma_f32_16x16x32_f16(af, bf, acc[j], 0, 0, 0);
            }
        }
    }

    #pragma unroll
    for (int j = 0; j < 4; ++j) {
        const int col  = bn + j * 16 + l16;
        const int row0 = bm + w * 16 + quad * 4;
        const float bv = bias[col];
        #pragma unroll
        for (int r = 0; r < 4; ++r) {
            const size_t off = (size_t)(row0 + r) * 768 + col;
            const float g = sigm(acc[j][r] + bv);
            const float o = g * X[off] + (1.f - g) * GC[off];
            H1[off]  = o;
            H16[off] = (_Float16)o;
        }
    }
}

// ---------------- D GEMM with fused final_combine epilogue ---------------------
// out[b,l,k,h] = sig(D[b,l,h] + E[b,k,h]) * h1[b,l,h] + (1-sig) * s[b,k,h]
__global__ __launch_bounds__(256) void gemm_final(
    const _Float16* __restrict__ A,   // h116 [2048][768]
    const _Float16* __restrict__ W,   // Wg2a16 [768][768]
    const float* __restrict__ bias,   // bg2
    const float* __restrict__ Ebuf,   // [256][768] fp32
    const float* __restrict__ Sbuf,   // s fp32 [256][768]
    const float* __restrict__ H1,     // h1 fp32 [2048][768]
    float* __restrict__ out)
{
    __shared__ union {
        struct { _Float16 As[64][72]; _Float16 Ws[64][72]; } a;
        float Ds[64][76];             // float4-aligned, benign banking
    } u;
    __shared__ float Es[32][64];
    __shared__ float Ss[32][64];

    const int t    = threadIdx.x;
    const int w    = t >> 6;
    const int lane = t & 63;
    const int quad = lane >> 4;
    const int l16  = lane & 15;
    const int bm   = blockIdx.y * 64;
    const int bn   = blockIdx.x * 64;
    const int bK   = (bm >> 8) * 32;  // batch * 32 row base into E/s

    const int sr = t >> 3;
    const int sk = (t & 7) * 8;

    // stage E and s slices (ready since gemm3 / input)
    #pragma unroll
    for (int i = 0; i < 2; ++i) {
        const int idx = t + i * 256;
        const int k = idx >> 4, c = (idx & 15) * 4;
        *(float4*)&Es[k][c] = *(const float4*)(Ebuf + (size_t)(bK + k) * 768 + bn + c);
        *(float4*)&Ss[k][c] = *(const float4*)(Sbuf + (size_t)(bK + k) * 768 + bn + c);
    }

    f32x4 acc[4] = {};

    half8 av[2], wv[2];
    #pragma unroll
    for (int i = 0; i < 2; ++i) {
        av[i] = *(const half8*)(A + (size_t)(bm + i * 32 + sr) * 768 + sk);
        wv[i] = *(const half8*)(W + (size_t)(bn + i * 32 + sr) * 768 + sk);
    }

    for (int k0 = 0; k0 < 768; k0 += 64) {
        __syncthreads();
        #pragma unroll
        for (int i = 0; i < 2; ++i) {
            *(half8*)&u.a.As[i * 32 + sr][sk] = av[i];
            *(half8*)&u.a.Ws[i * 32 + sr][sk] = wv[i];
        }
        __syncthreads();
        if (k0 + 64 < 768) {
            #pragma unroll
            for (int i = 0; i < 2; ++i) {
                av[i] = *(const half8*)(A + (size_t)(bm + i * 32 + sr) * 768 + k0 + 64 + sk);
                wv[i] = *(const half8*)(W + (size_t)(bn + i * 32 + sr) * 768 + k0 + 64 + sk);
            }
        }
        __builtin_amdgcn_sched_barrier(0);
        #pragma unroll
        for (int kk = 0; kk < 2; ++kk) {
            half8 af = *(const half8*)&u.a.As[w * 16 + l16][kk * 32 + quad * 8];
            #pragma unroll
            for (int j = 0; j < 4; ++j) {
                half8 bf = *(const half8*)&u.a.Ws[j * 16 + l16][kk * 32 + quad * 8];
                acc[j] = __builtin_amdgcn_mfma_f32_16x16x32_f16(af, bf, acc[j], 0, 0, 0);
            }
        }
    }

    __syncthreads();   // done reading As/Ws — union memory becomes Ds
    #pragma unroll
    for (int j = 0; j < 4; ++j) {
        const int col = j * 16 + l16;
        const float bv = bias[bn + col];
        #pragma unroll
        for (int r = 0; r < 4; ++r)
            u.Ds[w * 16 + quad * 4 + r][col] = acc[j][r] + bv;
    }
    __syncthreads();

    // re-layout: thread owns 4 consecutive rows x one float4 column group
    const int c  = (t & 15) * 4;
    const int r0 = (t >> 4) * 4;
    float4 d[4], h[4];
    #pragma unroll
    for (int rr = 0; rr < 4; ++rr) {
        d[rr] = *(const float4*)&u.Ds[r0 + rr][c];
        h[rr] = *(const float4*)(H1 + (size_t)(bm + r0 + rr) * 768 + bn + c);
    }
    float* ob = out + (size_t)(bm + r0) * 32 * 768 + bn + c;
    for (int k = 0; k < 32; ++k) {
        const float4 e  = *(const float4*)&Es[k][c];
        const float4 sv = *(const float4*)&Ss[k][c];
        #pragma unroll
        for (int rr = 0; rr < 4; ++rr) {
            float4 o; float g;
            g = sigm(d[rr].x + e.x); o.x = g * h[rr].x + (1.f - g) * sv.x;
            g = sigm(d[rr].y + e.y); o.y = g * h[rr].y + (1.f - g) * sv.y;
            g = sigm(d[rr].z + e.z); o.z = g * h[rr].z + (1.f - g) * sv.z;
            g = sigm(d[rr].w + e.w); o.w = g * h[rr].w + (1.f - g) * sv.w;
            *(float4*)(ob + (size_t)(rr * 32 + k) * 768) = o;
        }
    }
}

extern "C" void kernel_launch(void* const* d_in, const int* in_sizes, int n_in,
                              void* d_out, int out_size, void* d_ws, size_t ws_size,
                              hipStream_t stream) {
    const float* x   = (const float*)d_in[0];
    const float* s   = (const float*)d_in[1];
    const float* g   = (const float*)d_in[2];
    const float* Wq  = (const float*)d_in[3];
    const float* bq  = (const float*)d_in[4];
    const float* Wkv = (const float*)d_in[5];
    const float* bkv = (const float*)d_in[6];
    const float* Wg1 = (const float*)d_in[7];
    const float* bg1 = (const float*)d_in[8];
    const float* Wg2 = (const float*)d_in[9];
    const float* bg2 = (const float*)d_in[10];

    char* w = (char*)d_ws;
    _Float16* P16    = (_Float16*)(w + 0);         // [2048][128]        512 KB
    _Float16* xg16   = (_Float16*)(w + 524288);    // [2048][1536]       6.29 MB
    _Float16* g16    = (_Float16*)(w + 6815744);   // [1024][768]
    _Float16* s16    = (_Float16*)(w + 8388608);   // [256][768]
    _Float16* q16    = (_Float16*)(w + 8781824);   // [2048][768]
    _Float16* k16    = (_Float16*)(w + 11927552);  // [1024][768]
    _Float16* vT16   = (_Float16*)(w + 13500416);  // [8][768][128]
    _Float16* Wq16   = (_Float16*)(w + 15073280);  // [768][768]
    _Float16* Wkv16  = (_Float16*)(w + 16252928);  // [1536][768]
    _Float16* Wg116  = (_Float16*)(w + 18612224);  // [768][1536]
    _Float16* Wg2a16 = (_Float16*)(w + 20971520);  // [768][768]
    _Float16* Wg2b16 = (_Float16*)(w + 22151168);  // [768][768]
    float*    bufE   = (float*)(w + 23330816);     // [256][768] fp32
    float*    bufC   = (float*)(w + 24117248);     // gctx fp32 [2048][768]
    float*    bufB   = (float*)(w + 30408704);     // h1 fp32 [2048][768]
    _Float16* h116   = (_Float16*)(w + 36700160);  // [2048][768]
    float* out = (float*)d_out;

    const dim3 blk(256);

    // 1) all f32->f16 conversions in one dispatch
    ConvArgs ca;
    ca.src[0] = x;         ca.dst[0] = xg16;   ca.sstr[0] = 768;  ca.dstr[0] = 1536; ca.rl[0] = 768;
    ca.src[1] = g;         ca.dst[1] = g16;    ca.sstr[1] = 768;  ca.dstr[1] = 768;  ca.rl[1] = 768;
    ca.src[2] = s;         ca.dst[2] = s16;    ca.sstr[2] = 768;  ca.dstr[2] = 768;  ca.rl[2] = 768;
    ca.src[3] = Wq;        ca.dst[3] = Wq16;   ca.sstr[3] = 768;  ca.dstr[3] = 768;  ca.rl[3] = 768;
    ca.src[4] = Wkv;       ca.dst[4] = Wkv16;  ca.sstr[4] = 768;  ca.dstr[4] = 768;  ca.rl[4] = 768;
    ca.src[5] = Wg1;       ca.dst[5] = Wg116;  ca.sstr[5] = 1536; ca.dstr[5] = 1536; ca.rl[5] = 1536;
    ca.src[6] = Wg2;       ca.dst[6] = Wg2a16; ca.sstr[6] = 1536; ca.dstr[6] = 768;  ca.rl[6] = 768;
    ca.src[7] = Wg2 + 768; ca.dst[7] = Wg2b16; ca.sstr[7] = 1536; ca.dstr[7] = 768;  ca.rl[7] = 768;
    ca.cum[0] = 0;      ca.cum[1] = 196608; ca.cum[2] = 294912; ca.cum[3] = 319488;
    ca.cum[4] = 393216; ca.cum[5] = 540672; ca.cum[6] = 688128; ca.cum[7] = 761856;
    ca.cum[8] = 835584;
    conv_multi<<<dim3(3264), blk, 0, stream>>>(ca);

    // 2) q16, {k16,vT16}, E in ONE dispatch (64x64 tiles: 816 blocks)
    G3Args ga = {};
    ga.d[0] = { xg16, Wq16,   bq,      (void*)q16,  nullptr,     1536, 768, 0, 12 };  // q:  M=2048,N=768  -> 384
    ga.d[1] = { g16,  Wkv16,  bkv,     (void*)k16,  (void*)vT16, 768,  768, 1, 24 };  // kv: M=1024,N=1536 -> 384
    ga.d[2] = { s16,  Wg2b16, nullptr, (void*)bufE, nullptr,     768,  768, 2, 12 };  // E:  M=256, N=768  -> 48
    ga.cum[0] = 0; ga.cum[1] = 384; ga.cum[2] = 768; ga.cum[3] = 816;
    gemm3<<<dim3(816), blk, 0, stream>>>(ga);

    // 3) scores + softmax fused -> P16
    attn_scores_sm<<<dim3(4, 8), blk, 0, stream>>>(q16, k16, P16);

    // 4) gctx = P @ v (batched, 64x64 tiles: 384 blocks) -> bufC fp32 + xg16 cols 768.. f16
    gemm_gctx<<<dim3(12, 4, 8), blk, 0, stream>>>(
        P16, 128, 256L * 128, vT16, 128, 768L * 128,
        bufC, 768, 256L * 768, xg16 + 768, 1536, 256L * 1536);

    // 5) t1 = [x|gctx] @ Wg1^T + bg1, fused gate1 (384 blocks) -> bufB (h1) + h116
    gemm_gate1<<<dim3(12, 32), blk, 0, stream>>>(
        xg16, Wg116, bg1, x, bufC, bufB, h116);

    // 6) D = h1 @ Wg2a^T + bg2, fused final combine (384 blocks) -> out
    gemm_final<<<dim3(12, 32), blk, 0, stream>>>(
        h116, Wg2a16, bg2, bufE, s, bufB, out);
}